// Round 3
// baseline (343.511 us; speedup 1.0000x reference)
//
#include <hip/hip_runtime.h>
#include <stdint.h>
#include <type_traits>

// Problem constants (from reference): B,T,X,E,H,L = 4096,32,256,32,512,2
#define B_SZ 4096
#define T_SZ 32
#define X_SZ 256
#define E_SZ 32
#define H_SZ 512
#define BM   128     // batch rows per block (1 block/CU, LDS 133KB)
// A-tile LDS row stride: 512 bf16 = 1024B, +16B pad
#define AROW 1040

typedef __attribute__((ext_vector_type(8))) short  short8;   // 8 bf16 = 4 VGPR
typedef __attribute__((ext_vector_type(4))) float  floatx4;

// v_cvt_pk_bf16_f32: D[15:0]=bf16(a), D[31:16]=bf16(b), RNE (gfx950 HW instr)
__device__ __forceinline__ unsigned pk2(float a, float b) {
  unsigned r;
  asm("v_cvt_pk_bf16_f32 %0, %1, %2" : "=v"(r) : "v"(a), "v"(b));
  return r;
}

// ---------------------------------------------------------------------------
// Prep: fp32 weights -> bf16 MFMA B-fragments via LDS transpose. (unchanged)
// One block per chunk (32 k x 512 n). 1312 chunks total:
//   c in [0,288):    layer-1, c = e*9+kt. kt==0 -> masked W1t rows 0..31;
//                    kt>=1 -> W1x rows (kt-1)*32 .. +31.   out: wcat.
//   c in [288,1312): hidden, c-288 = (layer*32+e)*16 + kt. out: whf.
// Unit layout (contract with mlp_kernel): u = nb*64 + l,
//   n = nb*16 + (l&15), local k0 = (l>>4)*8, dword p covers k = k0+2p, k0+2p+1.
// ---------------------------------------------------------------------------
__global__ __launch_bounds__(256) void prep_kernel(
    const float* __restrict__ W1t, const float* __restrict__ W1x,
    const int* __restrict__ masks, const float* __restrict__ Wh,
    uint4* __restrict__ wcat, uint4* __restrict__ whf) {
  __shared__ unsigned lds[16 * 516];           // 33 KB
  const int c = blockIdx.x;
  const int t = threadIdx.x;

  const float* base;                           // row 0 of this chunk's 32 rows
  bool needMask = false;
  int e1 = 0;
  if (c >= 288) {
    int cc = c - 288;
    int le = cc >> 4, kt = cc & 15;            // le = layer*32 + e
    base = Wh + ((size_t)le * H_SZ + kt * 32) * H_SZ;
  } else {
    int e = c / 9, kt = c - e * 9;
    e1 = e;
    if (kt == 0) { base = W1t + (size_t)e * T_SZ * H_SZ; needMask = true; }
    else          base = W1x + ((size_t)e * X_SZ + (kt - 1) * 32) * H_SZ;
  }

#pragma unroll
  for (int i = 0; i < 8; ++i) {
    int g  = i * 256 + t;
    int k2 = g >> 7, np = g & 127;             // k2: wave-uniform
    const float* r0 = base + (size_t)(2 * k2) * H_SZ + np * 4;
    float4 a = *(const float4*)r0;
    float4 b = *(const float4*)(r0 + H_SZ);
    if (needMask) {
      float s0 = (float)masks[e1 * T_SZ + 2 * k2];
      float s1 = (float)masks[e1 * T_SZ + 2 * k2 + 1];
      a.x *= s0; a.y *= s0; a.z *= s0; a.w *= s0;
      b.x *= s1; b.y *= s1; b.z *= s1; b.w *= s1;
    }
    *(uint4*)&lds[k2 * 516 + np * 4] =
        make_uint4(pk2(a.x, b.x), pk2(a.y, b.y), pk2(a.z, b.z), pk2(a.w, b.w));
  }
  __syncthreads();

  uint4* outp = (c < 288) ? (wcat + (size_t)c * 2048)
                          : (whf + (size_t)(c - 288) * 2048);
  const int w = t >> 6, l = t & 63, q = l >> 4, l16 = l & 15;
#pragma unroll
  for (int j = 0; j < 8; ++j) {
    int nb = w * 8 + j;
    int n  = nb * 16 + l16;
    int kb = 4 * q;
    uint4 v;
    v.x = lds[(kb + 0) * 516 + n];
    v.y = lds[(kb + 1) * 516 + n];
    v.z = lds[(kb + 2) * 516 + n];
    v.w = lds[(kb + 3) * 516 + n];
    outp[nb * 64 + l] = v;                     // 16B/lane, lanes consecutive
  }
}

// ---------------------------------------------------------------------------
// Fused MLP v3: BM=128. block = (128-row batch tile, expert e), 1 block/CU.
// 8 waves; wave w owns cols [64w,64w+64) over all 128 rows: acc[8][4] 16x16
// tiles (128 AGPR). Per K-chunk: 32 MFMA vs 4 weight loads -> 2x arithmetic
// intensity of BM=64; weight L2 traffic halved (32 m-tiles/expert).
// gemm fully unrolled (compile-time NKT): ds_read offsets are immediates off
// 2 bases; weight loads are uniform-base + fixed-VGPR-offset (SALU chunk
// advance); B double-buffer via register renaming (no copies).
// Block map: all 32 CUs of an XCD run the same expert concurrently
// (weights 1.34MB << 4MB L2).
// ---------------------------------------------------------------------------
__global__ __launch_bounds__(512, 2) void mlp_kernel(
    const float* __restrict__ theta, const float* __restrict__ x,
    const short8* __restrict__ wcat, const short8* __restrict__ whf,
    const float* __restrict__ b1, const float* __restrict__ a1,
    const float* __restrict__ bh, const float* __restrict__ ah,
    const float* __restrict__ Wo, const float* __restrict__ bo,
    float* __restrict__ out) {
  __shared__ __align__(16) char smA[BM * AROW];   // 133120 B -> 1 block/CU
  const int tid = threadIdx.x;
  const int bid = blockIdx.x;
  const int xcd = bid & 7;
  const int t8  = bid >> 3;                       // per-XCD sequence 0..127
  const int e   = xcd * 4 + (t8 >> 5);            // 32 consecutive blocks/expert
  const int m0  = (t8 & 31) * BM;
  const int w   = tid >> 6, l = tid & 63, l16 = l & 15, quad = l >> 4;

  // ---- stage A0 = [theta | x] as bf16 (mask folded into prepped W1t) ----
  {
    int r = tid >> 2, c = tid & 3;                // 4 threads per row
    const float* tp = theta + (size_t)(m0 + r) * T_SZ + c * 8;
    float4 t0 = *(const float4*)tp;
    float4 t1 = *(const float4*)(tp + 4);
    *(uint4*)(smA + r * AROW + c * 16) =
        make_uint4(pk2(t0.x, t0.y), pk2(t0.z, t0.w), pk2(t1.x, t1.y), pk2(t1.z, t1.w));
    const float* xp = x + (size_t)(m0 + r) * X_SZ + c * 64;
#pragma unroll
    for (int j = 0; j < 8; ++j) {
      float4 a = *(const float4*)(xp + j * 8);
      float4 b = *(const float4*)(xp + j * 8 + 4);
      *(uint4*)(smA + r * AROW + 64 + c * 128 + j * 16) =
          make_uint4(pk2(a.x, a.y), pk2(a.z, a.w), pk2(b.x, b.y), pk2(b.z, b.w));
    }
  }
  __syncthreads();

  floatx4 acc[8][4];
  const int u0 = w * 256 + l;                     // weight unit index (this wave)
  const char* ar0 = smA + l16 * AROW + quad * 16; // A-frag bases (rows 0-63 / 64-127)
  const char* ar1 = ar0 + 4 * 16 * AROW;

  // GEMM over NKT K-chunks of 32, fully unrolled.
  auto gemm = [&](const short8* wbase, auto nktc) {
    constexpr int NKT = decltype(nktc)::value;
#pragma unroll
    for (int mb = 0; mb < 8; ++mb)
#pragma unroll
      for (int i = 0; i < 4; ++i) acc[mb][i] = (floatx4)(0.f);
    const short8* wu = wbase;                     // wave-uniform, SALU-advanced
    short8 bA[4], bB[4];
#pragma unroll
    for (int i = 0; i < 4; ++i) bA[i] = wu[u0 + i * 64];
#pragma unroll
    for (int kt = 0; kt < NKT; ++kt) {
      if (kt + 1 < NKT) {                         // prefetch next chunk
        const short8* wn = wu + 2048;
        if (kt & 1) {
#pragma unroll
          for (int i = 0; i < 4; ++i) bA[i] = wn[u0 + i * 64];
        } else {
#pragma unroll
          for (int i = 0; i < 4; ++i) bB[i] = wn[u0 + i * 64];
        }
      }
      short8 af[8];
#pragma unroll
      for (int mb = 0; mb < 4; ++mb)
        af[mb] = *(const short8*)(ar0 + mb * (16 * AROW) + kt * 64);
#pragma unroll
      for (int mb = 0; mb < 4; ++mb)
        af[mb + 4] = *(const short8*)(ar1 + mb * (16 * AROW) + kt * 64);
#pragma unroll
      for (int mb = 0; mb < 8; ++mb)
#pragma unroll
        for (int i = 0; i < 4; ++i)
          acc[mb][i] = __builtin_amdgcn_mfma_f32_16x16x32_bf16(
              af[mb], (kt & 1) ? bB[i] : bA[i], acc[mb][i], 0, 0, 0);
      wu += 2048;
    }
  };

  // bias + PReLU + bf16 pair-pack (shfl_xor 1) + write back into A buffer
  auto epi_store = [&](const float* bias, const float* slope) {
    float bb[4], aa[4];
#pragma unroll
    for (int i = 0; i < 4; ++i) {
      int col = w * 64 + i * 16 + l16;
      bb[i] = bias[col];
      aa[i] = slope[col];
    }
    __syncthreads();   // everyone done READING A before we overwrite
#pragma unroll
    for (int mb = 0; mb < 8; ++mb) {
#pragma unroll
      for (int i = 0; i < 4; ++i) {
        unsigned dw[4];
#pragma unroll
        for (int r = 0; r < 4; ++r) {
          float v = acc[mb][i][r] + bb[i];
          v = v >= 0.f ? v : aa[i] * v;
          float o  = __shfl_xor(v, 1, 64);
          float lo = (l16 & 1) ? o : v;
          float hi = (l16 & 1) ? v : o;
          dw[r] = pk2(lo, hi);
        }
        int col2  = w * 64 + i * 16 + (l16 & ~1);
        int rbase = (l16 & 1) * 2;                 // even lanes rows 0,1; odd 2,3
#pragma unroll
        for (int rr = 0; rr < 2; ++rr) {
          int row = mb * 16 + quad * 4 + rbase + rr;
          *(unsigned*)(smA + row * AROW + col2 * 2) = dw[rbase + rr];
        }
      }
    }
    __syncthreads();
  };

  // ---- layer 1: K = 288 (9 chunks) ----
  gemm(wcat + (size_t)e * 9 * 2048, std::integral_constant<int, 9>{});
  epi_store(b1 + (size_t)e * H_SZ, a1 + (size_t)e * H_SZ);
  // ---- hidden layer 0: K = 512 (16 chunks) ----
  gemm(whf + (size_t)e * 16 * 2048, std::integral_constant<int, 16>{});
  epi_store(bh + (size_t)e * H_SZ, ah + (size_t)e * H_SZ);
  // ---- hidden layer 1 + fused output dot (fp32, no bf16 rounding) ----
  gemm(whf + (size_t)(E_SZ + e) * 16 * 2048, std::integral_constant<int, 16>{});
  {
    float bb[4], aa[4], wo[4];
#pragma unroll
    for (int i = 0; i < 4; ++i) {
      int col = w * 64 + i * 16 + l16;
      bb[i] = bh[(size_t)(E_SZ + e) * H_SZ + col];
      aa[i] = ah[(size_t)(E_SZ + e) * H_SZ + col];
      wo[i] = Wo[(size_t)e * H_SZ + col];
    }
    float ps[8][4];
#pragma unroll
    for (int mb = 0; mb < 8; ++mb)
#pragma unroll
      for (int r = 0; r < 4; ++r) ps[mb][r] = 0.f;
#pragma unroll
    for (int mb = 0; mb < 8; ++mb)
#pragma unroll
      for (int i = 0; i < 4; ++i)
#pragma unroll
        for (int r = 0; r < 4; ++r) {
          float v = acc[mb][i][r] + bb[i];
          v = v >= 0.f ? v : aa[i] * v;
          ps[mb][r] += v * wo[i];
        }
    // reduce over the 16 lanes of each quad (cols within this wave's slice)
#pragma unroll
    for (int d = 1; d < 16; d <<= 1)
#pragma unroll
      for (int mb = 0; mb < 8; ++mb)
#pragma unroll
        for (int r = 0; r < 4; ++r) ps[mb][r] += __shfl_xor(ps[mb][r], d, 64);
    __syncthreads();                 // done reading A; reuse its storage
    float* scratch = (float*)smA;    // [128 rows][8 waves]
    if (l16 == 0) {
#pragma unroll
      for (int mb = 0; mb < 8; ++mb)
#pragma unroll
        for (int r = 0; r < 4; ++r)
          scratch[(mb * 16 + quad * 4 + r) * 8 + w] = ps[mb][r];
    }
    __syncthreads();
    if (tid < BM) {
      float s = 0.f;
#pragma unroll
      for (int ww = 0; ww < 8; ++ww) s += scratch[tid * 8 + ww];
      out[(size_t)(m0 + tid) * E_SZ + e] = s + bo[e];
    }
  }
}

// ---------------------------------------------------------------------------
extern "C" void kernel_launch(void* const* d_in, const int* in_sizes, int n_in,
                              void* d_out, int out_size, void* d_ws, size_t ws_size,
                              hipStream_t stream) {
  const float* theta = (const float*)d_in[0];
  const float* x     = (const float*)d_in[1];
  const int*   masks = (const int*)d_in[2];
  const float* W1t   = (const float*)d_in[3];
  const float* W1x   = (const float*)d_in[4];
  const float* b1    = (const float*)d_in[5];
  const float* a1    = (const float*)d_in[6];
  const float* Wh    = (const float*)d_in[7];
  const float* bh    = (const float*)d_in[8];
  const float* ah    = (const float*)d_in[9];
  const float* Wo    = (const float*)d_in[10];
  const float* bo    = (const float*)d_in[11];
  float* out = (float*)d_out;

  // ws layout: [0, 9.4MB) layer-1 frags; [9.4MB, 43MB) hidden frags.
  uint4* wcat = (uint4*)d_ws;
  uint4* whf  = (uint4*)((char*)d_ws + (size_t)E_SZ * 9 * 2048 * 16);

  // 288 layer-1 chunks + 1024 hidden chunks, one block each
  prep_kernel<<<1312, 256, 0, stream>>>(W1t, W1x, masks, Wh, wcat, whf);
  // 1024 blocks: 8 per XCD-round, 32 m-tiles x 32 experts
  mlp_kernel<<<1024, 512, 0, stream>>>(theta, x, (const short8*)wcat,
                                       (const short8*)whf, b1, a1, bh, ah, Wo, bo,
                                       out);
}